// Round 15
// baseline (1166.229 us; speedup 1.0000x reference)
//
#include <hip/hip_runtime.h>
#include <math.h>

#pragma clang fp contract(off)

// Problem constants (match reference)
#define PNUM 136500      // sum of f*f
#define HPNUM 68250      // PNUM/2 (exact)
#define BNUM 16
#define TOPK 5000
#define CAP 8192         // candidate capacity per image (power of 2 for bitonic)
#define NB2 1024         // histogram window buckets (covers ord16 of (0.01, 1.0))
#define B2BASE 0xBC00u   // window base: f2ord(0.01)>>16 = 0xBC23 >= 0xBC00
#define NWORDS 79        // ceil(5000/64)
#define GSTRIDE 32       // gcnt padding: 32 u32 = 128 B per image
#define CAPE 65536       // edge capacity per image (expected E ~ 1-3k)
#define NXB 128          // spatial x1 buckets
#define BSTRIDE 5120     // per-image bucket-array stride (>= TOPK)
#define EBUF 3072        // per-block LDS edge buffer

// Workspace layout (bytes). Boxes at front; hist/cut/gcnt/keys dead after
// k_decode. Bucket arrays overlay the grouped region (dead until k_nms2).
#define OFF_SC    ((size_t)0)
#define OFF_X1    (OFF_SC + 320000)
#define OFF_Y1    (OFF_X1 + 320000)
#define OFF_X2    (OFF_Y1 + 320000)
#define OFF_Y2    (OFF_X2 + 320000)
#define OFF_AREA  (OFF_Y2 + 320000)       // ends at 1,920,000
#define OFF_HIST  ((size_t)1920000)       // 65536
#define OFF_CUT   (OFF_HIST + 65536)      // 64
#define OFF_GCNT  (OFF_CUT + 64)          // 2048
#define OFF_KEYS  (OFF_GCNT + 2048)       // 1,048,576 -> ends 3,036,224
#define OFF_ECNT  ((size_t)3036224)       // 2048
#define OFF_EDGE  ((size_t)3038272)       // 16*65536*4 = 4,194,304
#define OFF_GRP   (OFF_EDGE + 4194304)    // 4,194,304 -> ends 11,426,880
// bucket arrays overlaid on GRP (dead before k_nms2 writes grouped):
#define OFF_BOFS  (OFF_GRP)               // 16*130*4 = 8320 (pad to 16384)
#define OFF_SIDX  (OFF_GRP + 16384)       // u32 [16*5120]
#define OFF_SBX1  (OFF_SIDX + 327680)
#define OFF_SBX2  (OFF_SBX1 + 327680)
#define OFF_SBY1  (OFF_SBX2 + 327680)
#define OFF_SBY2  (OFF_SBY1 + 327680)
#define OFF_SBAR  (OFF_SBY2 + 327680)     // ends GRP+1,982,464 < GRP+4,194,304

__device__ __forceinline__ unsigned f2ord(float f) {
    unsigned u = __float_as_uint(f);
    return (u & 0x80000000u) ? ~u : (u | 0x80000000u);
}
__device__ __forceinline__ float ord2f(unsigned o) {
    unsigned u = (o & 0x80000000u) ? (o ^ 0x80000000u) : ~o;
    return __uint_as_float(u);
}
// monotone x1 -> bucket map; identical in k_bucket and k_pair
__device__ __forceinline__ int bucketOf(float x) {
    int b = (int)((x + 0.6f) * 71.111115f);   // 128 buckets over [-0.6, 1.2]
    return (b < 0) ? 0 : ((b > 127) ? 127 : b);
}

// K1: per-image histogram over the 1024-bucket window in LDS, then one
// contiguous atomic merge per block.
__global__ void __launch_bounds__(256) k_hist(const float* __restrict__ conf,
                                              unsigned* __restrict__ hist) {
    __shared__ unsigned lh[NB2];
    int img = blockIdx.y;
    for (int i = threadIdx.x; i < NB2; i += 256) lh[i] = 0;
    __syncthreads();
    const float4* src = (const float4*)(conf + (size_t)img * PNUM * 2);
    int stride = gridDim.x * 256;
    for (int q = blockIdx.x * 256 + threadIdx.x; q < HPNUM; q += stride) {
        float4 v = src[q];
        if (v.y > 0.01f) atomicAdd(&lh[(f2ord(v.y) >> 16) - B2BASE], 1u);
        if (v.w > 0.01f) atomicAdd(&lh[(f2ord(v.w) >> 16) - B2BASE], 1u);
    }
    __syncthreads();
    unsigned* h = hist + (size_t)img * NB2;
    for (int i = threadIdx.x; i < NB2; i += 256) {
        unsigned c = lh[i];
        if (c) atomicAdd(&h[i], c);
    }
}

// K2: find cutoff (absolute 16-bit bucket) so count(bucket >= cut) >= TOPK
__global__ void __launch_bounds__(256) k_cutoff(const unsigned* __restrict__ hist,
                                                unsigned* __restrict__ cut) {
    __shared__ unsigned csum[256];
    int img = blockIdx.x;
    int t = threadIdx.x;
    const unsigned* h = hist + (size_t)img * NB2;
    unsigned s = 0;
    for (int b = 0; b < 4; ++b) s += h[t * 4 + b];
    csum[t] = s;
    __syncthreads();
    if (t == 0) {
        unsigned acc = 0, before = 0;
        int c = -1;
        for (int cc = 255; cc >= 0; --cc) {
            if (acc + csum[cc] >= (unsigned)TOPK) { c = cc; before = acc; break; }
            acc += csum[cc];
        }
        unsigned cutb = B2BASE;            // fallback: take all valid
        if (c >= 0) {
            unsigned s2 = before;
            cutb = B2BASE + (unsigned)c * 4u;
            for (int b = c * 4 + 3; b >= c * 4; --b) {
                s2 += h[b];
                if (s2 >= (unsigned)TOPK) { cutb = B2BASE + (unsigned)b; break; }
            }
        }
        cut[img] = cutb;
    }
}

// K3: gather candidate keys (ord<<32)|~p for buckets >= cutoff.
__global__ void __launch_bounds__(256) k_gather(
        const float* __restrict__ conf, const unsigned* __restrict__ cut,
        unsigned* __restrict__ gcnt, unsigned long long* __restrict__ keys) {
    __shared__ unsigned wbase[4];
    __shared__ unsigned bbase;
    int q = blockIdx.x * 256 + threadIdx.x;
    int img = blockIdx.y;
    int lane = threadIdx.x & 63, wid = threadIdx.x >> 6;
    unsigned cutb = cut[img];
    bool c0 = false, c1 = false;
    unsigned o0 = 0, o1 = 0;
    int p0 = 0, p1 = 0;
    if (q < HPNUM) {
        float4 v = ((const float4*)(conf + (size_t)img * PNUM * 2))[q];
        p0 = 2 * q; p1 = 2 * q + 1;
        if (v.y > 0.01f) { o0 = f2ord(v.y); c0 = (o0 >> 16) >= cutb; }
        if (v.w > 0.01f) { o1 = f2ord(v.w); c1 = (o1 >> 16) >= cutb; }
    }
    unsigned long long b0 = __ballot(c0), b1 = __ballot(c1);
    if (lane == 0) wbase[wid] = (unsigned)(__popcll(b0) + __popcll(b1));
    __syncthreads();
    if (threadIdx.x == 0) {
        unsigned t0 = wbase[0], t1 = wbase[1], t2 = wbase[2], t3 = wbase[3];
        unsigned tot = t0 + t1 + t2 + t3;
        unsigned base = tot ? atomicAdd(&gcnt[(size_t)img * GSTRIDE], tot) : 0u;
        bbase = base;
        wbase[0] = 0; wbase[1] = t0; wbase[2] = t0 + t1; wbase[3] = t0 + t1 + t2;
    }
    __syncthreads();
    unsigned mybase = bbase + wbase[wid];
    unsigned long long lt = (lane == 0) ? 0ull : ((1ull << lane) - 1ull);
    if (c0) {
        unsigned pos = mybase + (unsigned)__popcll(b0 & lt);
        if (pos < (unsigned)CAP)
            keys[(size_t)img * CAP + pos] =
                ((unsigned long long)o0 << 32) | (unsigned)(~(unsigned)p0);
    }
    if (c1) {
        unsigned pos = mybase + (unsigned)__popcll(b0) + (unsigned)__popcll(b1 & lt);
        if (pos < (unsigned)CAP)
            keys[(size_t)img * CAP + pos] =
                ((unsigned long long)o1 << 32) | (unsigned)(~(unsigned)p1);
    }
}

// ---- Multi-block bitonic sort of each image's 8192 keys (descending) ----

// K4a: stages k=2..2048 (all chunk-local). 4 chunks of 2048 per image.
__global__ void __launch_bounds__(1024) k_sloc1(
        unsigned long long* __restrict__ keys, const unsigned* __restrict__ gcnt) {
    __shared__ unsigned long long sk[2048];
    int img = blockIdx.x >> 2;
    int base = (blockIdx.x & 3) * 2048;
    int N = (int)min(gcnt[(size_t)img * GSTRIDE], (unsigned)CAP);
    unsigned long long* kp = keys + (size_t)img * CAP;
    int tid = threadIdx.x;
    for (int i = tid; i < 2048; i += 1024)
        sk[i] = (base + i < N) ? kp[base + i] : 0ull;
    __syncthreads();
    for (int k = 2; k <= 2048; k <<= 1) {
        for (int j = k >> 1; j > 0; j >>= 1) {
            int i = ((tid & ~(j - 1)) << 1) | (tid & (j - 1));
            int p = i | j;
            bool desc = (((base + i) & k) == 0);
            unsigned long long a = sk[i], b = sk[p];
            bool sw = desc ? (a < b) : (a > b);
            if (sw) { sk[i] = b; sk[p] = a; }
            __syncthreads();
        }
    }
    for (int i = tid; i < 2048; i += 1024) kp[base + i] = sk[i];
}

// K4b: stage k=4096 complete (j=2048..1). 2 half-spans of 4096 per image.
__global__ void __launch_bounds__(1024) k_sloc2(unsigned long long* __restrict__ keys) {
    __shared__ unsigned long long sk[4096];
    int img = blockIdx.x >> 1;
    int base = (blockIdx.x & 1) * 4096;
    unsigned long long* kp = keys + (size_t)img * CAP + base;
    int tid = threadIdx.x;
    for (int i = tid; i < 4096; i += 1024) sk[i] = kp[i];
    __syncthreads();
    for (int j = 2048; j > 0; j >>= 1) {
        for (int t = tid; t < 2048; t += 1024) {
            int i = ((t & ~(j - 1)) << 1) | (t & (j - 1));
            int p = i | j;
            bool desc = (((base + i) & 4096) == 0);
            unsigned long long a = sk[i], b = sk[p];
            bool sw = desc ? (a < b) : (a > b);
            if (sw) { sk[i] = b; sk[p] = a; }
        }
        __syncthreads();
    }
    for (int i = tid; i < 4096; i += 1024) kp[i] = sk[i];
}

// K4c: stage k=8192 complete (j=4096..1, all descending). 1 block per image.
__global__ void __launch_bounds__(1024) k_sloc3(unsigned long long* __restrict__ keys) {
    __shared__ unsigned long long sk[CAP];
    unsigned long long* kp = keys + (size_t)blockIdx.x * CAP;
    int tid = threadIdx.x;
    for (int i = tid; i < CAP; i += 1024) sk[i] = kp[i];
    __syncthreads();
    for (int j = 4096; j > 0; j >>= 1) {
        for (int t = tid; t < 4096; t += 1024) {
            int i = ((t & ~(j - 1)) << 1) | (t & (j - 1));
            int p = i | j;
            unsigned long long a = sk[i], b = sk[p];
            if (a < b) { sk[i] = b; sk[p] = a; }     // always descending
        }
        __syncthreads();
    }
    for (int i = tid; i < CAP; i += 1024) kp[i] = sk[i];
}

// K4d: decode sorted top-5000 keys -> SC/X1/Y1/X2/Y2/AREA (fully parallel)
__global__ void __launch_bounds__(256) k_decode(
        const unsigned long long* __restrict__ keys,
        const float* __restrict__ loc, const float* __restrict__ pri,
        float* __restrict__ SC, float* __restrict__ X1, float* __restrict__ Y1,
        float* __restrict__ X2, float* __restrict__ Y2, float* __restrict__ AREA) {
    int gidx = blockIdx.x * 256 + threadIdx.x;
    if (gidx >= BNUM * TOPK) return;
    int img = gidx / TOPK;
    int r = gidx - img * TOPK;
    unsigned long long key = keys[(size_t)img * CAP + r];
    size_t o = (size_t)img * TOPK + r;
    if (key != 0ull) {
        unsigned ordv = (unsigned)(key >> 32);
        float s = ord2f(ordv);
        unsigned p = ~(unsigned)(key & 0xFFFFFFFFull);
        const float* lp = loc + ((size_t)img * PNUM + p) * 4;
        const float* pp = pri + (size_t)p * 4;
        float lx = lp[0], ly = lp[1], lw = lp[2], lh = lp[3];
        float px = pp[0], py = pp[1], pw = pp[2], ph = pp[3];
        float cx = px + (lx * 0.1f) * pw;
        float cy = py + (ly * 0.1f) * ph;
        float w = pw * expf(lw * 0.2f);
        float h = ph * expf(lh * 0.2f);
        float x1 = cx - w * 0.5f;
        float y1 = cy - h * 0.5f;
        float x2 = x1 + w;
        float y2 = y1 + h;
        SC[o] = s; X1[o] = x1; Y1[o] = y1; X2[o] = x2; Y2[o] = y2;
        AREA[o] = (x2 - x1) * (y2 - y1);
    } else {
        SC[o] = -1.0f; X1[o] = 0.f; Y1[o] = 0.f; X2[o] = 0.f; Y2[o] = 0.f;
        AREA[o] = 0.f;
    }
}

// K5a: spatial bucketing by x1 (counting sort into 128 buckets), with
// gathered box copies so the pair scan reads contiguously. 1 block/image.
__global__ void __launch_bounds__(256) k_bucket(
        const float* __restrict__ X1, const float* __restrict__ X2,
        const float* __restrict__ Y1, const float* __restrict__ Y2,
        const float* __restrict__ AREA,
        unsigned* __restrict__ bofs, unsigned* __restrict__ sidx,
        float* __restrict__ sbx1, float* __restrict__ sbx2,
        float* __restrict__ sby1, float* __restrict__ sby2,
        float* __restrict__ sbar) {
    __shared__ unsigned bcnt[NXB], bpre[NXB + 1], bcur[NXB];
    int img = blockIdx.x;
    int tid = threadIdx.x;
    if (tid < NXB) bcnt[tid] = 0;
    __syncthreads();
    size_t ib = (size_t)img * TOPK;
    for (int r = tid; r < TOPK; r += 256)
        atomicAdd(&bcnt[bucketOf(X1[ib + r])], 1u);
    __syncthreads();
    if (tid == 0) {
        unsigned a = 0;
        for (int b = 0; b < NXB; ++b) { bpre[b] = a; a += bcnt[b]; }
        bpre[NXB] = a;
    }
    __syncthreads();
    if (tid < NXB) bcur[tid] = bpre[tid];
    if (tid <= NXB) bofs[img * 130 + tid] = bpre[tid];
    __syncthreads();
    int base = img * BSTRIDE;
    for (int r = tid; r < TOPK; r += 256) {
        float x = X1[ib + r];
        unsigned s = atomicAdd(&bcur[bucketOf(x)], 1u);
        sidx[base + s] = (unsigned)r;
        sbx1[base + s] = x;
        sbx2[base + s] = X2[ib + r];
        sby1[base + s] = Y1[ib + r];
        sby2[base + s] = Y2[ib + r];
        sbar[base + s] = AREA[ib + r];
    }
}

// K5b: bucketed pair search. Thread r scans buckets [bucket(x1_r),
// bucket(x2_r)]; pair emitted by the box with smaller x1 (tie: smaller
// original index) -> each x-overlapping pair tested exactly once. IoU math
// bit-identical to reference (fmin/fmax/add commutative). Edges buffered in
// LDS, flushed with ONE global atomicAdd per block.
__global__ void __launch_bounds__(256) k_pair(
        const float* __restrict__ X1, const float* __restrict__ X2,
        const float* __restrict__ Y1, const float* __restrict__ Y2,
        const float* __restrict__ AREA,
        const unsigned* __restrict__ bofs, const unsigned* __restrict__ sidx,
        const float* __restrict__ sbx1, const float* __restrict__ sbx2,
        const float* __restrict__ sby1, const float* __restrict__ sby2,
        const float* __restrict__ sbar,
        unsigned* __restrict__ ecnt, unsigned* __restrict__ edges) {
    __shared__ unsigned ebuf[EBUF];
    __shared__ unsigned ecl, ebase;
    int img = blockIdx.y;
    int r = blockIdx.x * 256 + threadIdx.x;
    if (threadIdx.x == 0) ecl = 0;
    __syncthreads();
    unsigned* ec = ecnt + (size_t)img * GSTRIDE;
    unsigned* eg = edges + (size_t)img * CAPE;
    if (r < TOPK) {
        size_t ib = (size_t)img * TOPK;
        float x1 = X1[ib + r], x2 = X2[ib + r];
        float y1 = Y1[ib + r], y2 = Y2[ib + r];
        float ar = AREA[ib + r];
        int b1 = bucketOf(x1), b2 = bucketOf(x2);
        const unsigned* bo = bofs + img * 130;
        int base = img * BSTRIDE;
        for (int b = b1; b <= b2; ++b) {
            unsigned s0 = bo[b], s1 = bo[b + 1];
            for (unsigned s = s0; s < s1; ++s) {
                float bx1 = sbx1[base + s];
                if (bx1 < x1) continue;              // partner emits
                unsigned r2 = sidx[base + s];
                if (bx1 == x1 && r2 <= (unsigned)r) continue;
                float bx2 = sbx2[base + s];
                float dx = fminf(x2, bx2) - fmaxf(x1, bx1);
                if (!(dx > 0.0f)) continue;
                float by1 = sby1[base + s], by2 = sby2[base + s];
                float dy = fminf(y2, by2) - fmaxf(y1, by1);
                if (!(dy > 0.0f)) continue;
                float inter = dx * dy;
                float iou = inter / (sbar[base + s] + ar - inter);
                if (iou > 0.3f) {
                    unsigned su = ((unsigned)r < r2) ? (unsigned)r : r2;
                    unsigned vi = ((unsigned)r < r2) ? r2 : (unsigned)r;
                    unsigned edge = (vi << 13) | su;
                    unsigned p = atomicAdd(&ecl, 1u);
                    if (p < (unsigned)EBUF) ebuf[p] = edge;
                    else {
                        unsigned gp = atomicAdd(ec, 1u);
                        if (gp < (unsigned)CAPE) eg[gp] = edge;
                    }
                }
            }
        }
    }
    __syncthreads();
    unsigned n = min(ecl, (unsigned)EBUF);
    if (threadIdx.x == 0 && n) ebase = atomicAdd(ec, n);
    __syncthreads();
    for (unsigned i = threadIdx.x; i < n; i += 256) {
        unsigned p = ebase + i;
        if (p < (unsigned)CAPE) eg[p] = ebuf[i];
    }
}

// K5c: sparse greedy resolve + compaction. One block (256) per image.
__global__ void __launch_bounds__(256) k_nms2(
        const float* __restrict__ SC, const float* __restrict__ X1,
        const float* __restrict__ Y1, const float* __restrict__ X2,
        const float* __restrict__ Y2,
        const unsigned* __restrict__ ecnt, const unsigned* __restrict__ edges,
        unsigned* __restrict__ grouped, float* __restrict__ out) {
    __shared__ unsigned cnt[80], ofs[80], cur[80];
    __shared__ unsigned long long keepw[80];
    __shared__ unsigned pfx[80];
    __shared__ unsigned inLo[64], inHi[64];
    __shared__ unsigned remS[2];
    int img = blockIdx.x;
    int tid = threadIdx.x;
    int l = tid & 63;
    int wid = tid >> 6;
    size_t ib = (size_t)img * TOPK;
    const float* sc = SC + ib;

    // A: counting sort of edges by victim tile (v>>6 == edge>>19)
    if (tid < 80) cnt[tid] = 0;
    __syncthreads();
    unsigned E = min(ecnt[(size_t)img * GSTRIDE], (unsigned)CAPE);
    const unsigned* eimg = edges + (size_t)img * CAPE;
    unsigned* gimg = grouped + (size_t)img * CAPE;
    for (unsigned e = tid; e < E; e += 256) atomicAdd(&cnt[eimg[e] >> 19], 1u);
    __syncthreads();
    if (tid == 0) {
        unsigned a = 0;
        for (int w = 0; w < NWORDS; ++w) { ofs[w] = a; a += cnt[w]; }
    }
    __syncthreads();
    if (tid < 80) cur[tid] = ofs[tid];
    __syncthreads();
    for (unsigned e = tid; e < E; e += 256) {
        unsigned ed = eimg[e];
        unsigned p = atomicAdd(&cur[ed >> 19], 1u);
        gimg[p] = ed;
    }
    __syncthreads();

    // B: wave-0 serial-over-tiles resolve
    if (wid == 0) {
        for (int t = 0; t < NWORDS; ++t) {
            inLo[l] = 0; inHi[l] = 0;
            if (l < 2) remS[l] = 0;
            int row = t * 64 + l;
            bool valid = (row < TOPK) && (sc[row] > 0.01f);
            unsigned c = cnt[t], o = ofs[t];
            for (unsigned k = l; k < c; k += 64) {
                unsigned ed = gimg[o + k];
                unsigned v = ed >> 13, s = ed & 8191u;
                unsigned vb = v & 63u, sb = s & 63u;
                int st = (int)(s >> 6);
                if (st == t) {
                    if (sb < 32) atomicOr(&inLo[vb], 1u << sb);
                    else         atomicOr(&inHi[vb], 1u << (sb - 32));
                } else {
                    unsigned long long kw = keepw[st];   // finalized (st < t)
                    if ((kw >> sb) & 1ull) {
                        if (vb < 32) atomicOr(&remS[0], 1u << vb);
                        else         atomicOr(&remS[1], 1u << (vb - 32));
                    }
                }
            }
            __builtin_amdgcn_s_waitcnt(0);   // drain LDS atomics before reads
            unsigned long long inW =
                ((unsigned long long)inHi[l] << 32) | inLo[l];
            unsigned long long remW =
                ((unsigned long long)remS[1] << 32) | remS[0];
            bool alive = valid && !((remW >> l) & 1ull);
            while (true) {                   // exact ascending greedy
                unsigned long long aliveW = __ballot(alive);
                unsigned long long pend =
                    __ballot(alive && ((inW & aliveW) != 0ull));
                if (!pend) break;
                int v = __builtin_ctzll(pend);
                if (l == v) alive = false;
            }
            unsigned long long kwv = __ballot(alive);
            if (l == 0) keepw[t] = kwv;
        }
    }
    __syncthreads();

    // C: prefix + compacted output write
    if (tid == 0) {
        unsigned acc = 0;
        for (int w = 0; w < NWORDS; ++w) { pfx[w] = acc; acc += (unsigned)__popcll(keepw[w]); }
    }
    __syncthreads();
    const float* x1 = X1 + ib; const float* y1 = Y1 + ib;
    const float* x2 = X2 + ib; const float* y2 = Y2 + ib;
    float* op = out + (((size_t)img * 2) + 1) * TOPK * 5;
    for (int w = wid; w < NWORDS; w += 4) {
        unsigned long long kw = keepw[w];
        if (!kw) continue;
        int row = w * 64 + l;
        if ((kw >> l) & 1ull) {
            int rank = (int)pfx[w] + (int)__popcll(kw & ((1ull << l) - 1ull));
            float* r = op + (size_t)rank * 5;
            r[0] = sc[row]; r[1] = x1[row]; r[2] = y1[row];
            r[3] = x2[row]; r[4] = y2[row];
        }
    }
}

extern "C" void kernel_launch(void* const* d_in, const int* in_sizes, int n_in,
                              void* d_out, int out_size, void* d_ws, size_t ws_size,
                              hipStream_t stream) {
    (void)in_sizes; (void)n_in; (void)ws_size;
    const float* loc  = (const float*)d_in[0];   // (16, 136500, 4)
    const float* conf = (const float*)d_in[1];   // (16*136500, 2)
    const float* pri  = (const float*)d_in[2];   // (136500, 4)
    float* out = (float*)d_out;                  // (16, 2, 5000, 5)
    char* ws = (char*)d_ws;

    float* SC   = (float*)(ws + OFF_SC);
    float* X1   = (float*)(ws + OFF_X1);
    float* Y1   = (float*)(ws + OFF_Y1);
    float* X2   = (float*)(ws + OFF_X2);
    float* Y2   = (float*)(ws + OFF_Y2);
    float* AREA = (float*)(ws + OFF_AREA);
    unsigned* hist = (unsigned*)(ws + OFF_HIST);
    unsigned* cut  = (unsigned*)(ws + OFF_CUT);
    unsigned* gcnt = (unsigned*)(ws + OFF_GCNT);
    unsigned long long* keys = (unsigned long long*)(ws + OFF_KEYS);
    unsigned* ecnt = (unsigned*)(ws + OFF_ECNT);
    unsigned* edges = (unsigned*)(ws + OFF_EDGE);
    unsigned* grouped = (unsigned*)(ws + OFF_GRP);
    unsigned* bofs = (unsigned*)(ws + OFF_BOFS);
    unsigned* sidx = (unsigned*)(ws + OFF_SIDX);
    float* sbx1 = (float*)(ws + OFF_SBX1);
    float* sbx2 = (float*)(ws + OFF_SBX2);
    float* sby1 = (float*)(ws + OFF_SBY1);
    float* sby2 = (float*)(ws + OFF_SBY2);
    float* sbar = (float*)(ws + OFF_SBAR);

    hipMemsetAsync(d_out, 0, (size_t)out_size * sizeof(float), stream);
    // zero hist+cut+gcnt (+keys harmlessly) + ecnt in one contiguous range
    hipMemsetAsync(ws + OFF_HIST, 0, (OFF_ECNT + 2048) - OFF_HIST, stream);

    dim3 gh1(16, BNUM);                          // 16 grid-stride blocks/image
    k_hist<<<gh1, 256, 0, stream>>>(conf, hist);
    k_cutoff<<<BNUM, 256, 0, stream>>>(hist, cut);
    dim3 gh2((HPNUM + 255) / 256, BNUM);
    k_gather<<<gh2, 256, 0, stream>>>(conf, cut, gcnt, keys);
    // multi-block bitonic sort + parallel decode
    k_sloc1<<<BNUM * 4, 1024, 0, stream>>>(keys, gcnt);
    k_sloc2<<<BNUM * 2, 1024, 0, stream>>>(keys);
    k_sloc3<<<BNUM, 1024, 0, stream>>>(keys);
    k_decode<<<(BNUM * TOPK + 255) / 256, 256, 0, stream>>>(
        keys, loc, pri, SC, X1, Y1, X2, Y2, AREA);

    // sparse NMS: spatial bucketing + bucketed pair search + resolve
    k_bucket<<<BNUM, 256, 0, stream>>>(X1, X2, Y1, Y2, AREA,
                                       bofs, sidx, sbx1, sbx2, sby1, sby2, sbar);
    dim3 pg((TOPK + 255) / 256, BNUM);
    k_pair<<<pg, 256, 0, stream>>>(X1, X2, Y1, Y2, AREA,
                                   bofs, sidx, sbx1, sbx2, sby1, sby2, sbar,
                                   ecnt, edges);
    k_nms2<<<BNUM, 256, 0, stream>>>(SC, X1, Y1, X2, Y2, ecnt, edges, grouped, out);
}

// Round 16
// 334.503 us; speedup vs baseline: 3.4865x; 3.4865x over previous
//
#include <hip/hip_runtime.h>
#include <math.h>

#pragma clang fp contract(off)

// Problem constants (match reference)
#define PNUM 136500      // sum of f*f
#define HPNUM 68250      // PNUM/2 (exact)
#define BNUM 16
#define TOPK 5000
#define CAP 8192         // candidate capacity per image (power of 2 for bitonic)
#define NB2 1024         // histogram window buckets (covers ord16 of (0.01, 1.0))
#define B2BASE 0xBC00u   // window base: f2ord(0.01)>>16 = 0xBC23 >= 0xBC00
#define NWORDS 79        // ceil(5000/64)
#define GSTRIDE 32       // gcnt padding: 32 u32 = 128 B per image
#define CAPE 65536       // edge capacity per image (expected E ~ 1-3k)
#define NXB 128          // spatial x1 buckets
#define BSTRIDE 5120     // per-image bucket-array stride (>= TOPK)
#define EBUF 3072        // per-block LDS edge buffer

// Workspace layout (bytes). Boxes at front; hist/cut/gcnt/keys dead after
// k_decode. Bucket arrays overlay the grouped region (dead until k_nms2).
#define OFF_SC    ((size_t)0)
#define OFF_X1    (OFF_SC + 320000)
#define OFF_Y1    (OFF_X1 + 320000)
#define OFF_X2    (OFF_Y1 + 320000)
#define OFF_Y2    (OFF_X2 + 320000)
#define OFF_AREA  (OFF_Y2 + 320000)       // ends at 1,920,000
#define OFF_HIST  ((size_t)1920000)       // 65536
#define OFF_CUT   (OFF_HIST + 65536)      // 64
#define OFF_GCNT  (OFF_CUT + 64)          // 2048
#define OFF_KEYS  (OFF_GCNT + 2048)       // 1,048,576 -> ends 3,036,224
#define OFF_ECNT  ((size_t)3036224)       // 2048
#define OFF_EDGE  ((size_t)3038272)       // 16*65536*4 = 4,194,304
#define OFF_GRP   (OFF_EDGE + 4194304)    // 4,194,304 -> ends 11,426,880
// bucket arrays overlaid on GRP (dead before k_nms2 writes grouped):
#define OFF_BOFS  (OFF_GRP)               // 16*130*4 = 8320 (pad to 16384)
#define OFF_SIDX  (OFF_GRP + 16384)       // u32 [16*5120]
#define OFF_SBX1  (OFF_SIDX + 327680)
#define OFF_SBX2  (OFF_SBX1 + 327680)
#define OFF_SBY1  (OFF_SBX2 + 327680)
#define OFF_SBY2  (OFF_SBY1 + 327680)
#define OFF_SBAR  (OFF_SBY2 + 327680)     // ends GRP+1,982,464 < GRP+4,194,304

__device__ __forceinline__ unsigned f2ord(float f) {
    unsigned u = __float_as_uint(f);
    return (u & 0x80000000u) ? ~u : (u | 0x80000000u);
}
__device__ __forceinline__ float ord2f(unsigned o) {
    unsigned u = (o & 0x80000000u) ? (o ^ 0x80000000u) : ~o;
    return __uint_as_float(u);
}
// monotone x1 -> bucket map; identical in k_bucket and k_pair2
__device__ __forceinline__ int bucketOf(float x) {
    int b = (int)((x + 0.6f) * 71.111115f);   // 128 buckets over [-0.6, 1.2]
    return (b < 0) ? 0 : ((b > 127) ? 127 : b);
}

// K1: per-image histogram over the 1024-bucket window in LDS, then one
// contiguous atomic merge per block.
__global__ void __launch_bounds__(256) k_hist(const float* __restrict__ conf,
                                              unsigned* __restrict__ hist) {
    __shared__ unsigned lh[NB2];
    int img = blockIdx.y;
    for (int i = threadIdx.x; i < NB2; i += 256) lh[i] = 0;
    __syncthreads();
    const float4* src = (const float4*)(conf + (size_t)img * PNUM * 2);
    int stride = gridDim.x * 256;
    for (int q = blockIdx.x * 256 + threadIdx.x; q < HPNUM; q += stride) {
        float4 v = src[q];
        if (v.y > 0.01f) atomicAdd(&lh[(f2ord(v.y) >> 16) - B2BASE], 1u);
        if (v.w > 0.01f) atomicAdd(&lh[(f2ord(v.w) >> 16) - B2BASE], 1u);
    }
    __syncthreads();
    unsigned* h = hist + (size_t)img * NB2;
    for (int i = threadIdx.x; i < NB2; i += 256) {
        unsigned c = lh[i];
        if (c) atomicAdd(&h[i], c);
    }
}

// K2: find cutoff (absolute 16-bit bucket) so count(bucket >= cut) >= TOPK
__global__ void __launch_bounds__(256) k_cutoff(const unsigned* __restrict__ hist,
                                                unsigned* __restrict__ cut) {
    __shared__ unsigned csum[256];
    int img = blockIdx.x;
    int t = threadIdx.x;
    const unsigned* h = hist + (size_t)img * NB2;
    unsigned s = 0;
    for (int b = 0; b < 4; ++b) s += h[t * 4 + b];
    csum[t] = s;
    __syncthreads();
    if (t == 0) {
        unsigned acc = 0, before = 0;
        int c = -1;
        for (int cc = 255; cc >= 0; --cc) {
            if (acc + csum[cc] >= (unsigned)TOPK) { c = cc; before = acc; break; }
            acc += csum[cc];
        }
        unsigned cutb = B2BASE;            // fallback: take all valid
        if (c >= 0) {
            unsigned s2 = before;
            cutb = B2BASE + (unsigned)c * 4u;
            for (int b = c * 4 + 3; b >= c * 4; --b) {
                s2 += h[b];
                if (s2 >= (unsigned)TOPK) { cutb = B2BASE + (unsigned)b; break; }
            }
        }
        cut[img] = cutb;
    }
}

// K3: gather candidate keys (ord<<32)|~p for buckets >= cutoff.
__global__ void __launch_bounds__(256) k_gather(
        const float* __restrict__ conf, const unsigned* __restrict__ cut,
        unsigned* __restrict__ gcnt, unsigned long long* __restrict__ keys) {
    __shared__ unsigned wbase[4];
    __shared__ unsigned bbase;
    int q = blockIdx.x * 256 + threadIdx.x;
    int img = blockIdx.y;
    int lane = threadIdx.x & 63, wid = threadIdx.x >> 6;
    unsigned cutb = cut[img];
    bool c0 = false, c1 = false;
    unsigned o0 = 0, o1 = 0;
    int p0 = 0, p1 = 0;
    if (q < HPNUM) {
        float4 v = ((const float4*)(conf + (size_t)img * PNUM * 2))[q];
        p0 = 2 * q; p1 = 2 * q + 1;
        if (v.y > 0.01f) { o0 = f2ord(v.y); c0 = (o0 >> 16) >= cutb; }
        if (v.w > 0.01f) { o1 = f2ord(v.w); c1 = (o1 >> 16) >= cutb; }
    }
    unsigned long long b0 = __ballot(c0), b1 = __ballot(c1);
    if (lane == 0) wbase[wid] = (unsigned)(__popcll(b0) + __popcll(b1));
    __syncthreads();
    if (threadIdx.x == 0) {
        unsigned t0 = wbase[0], t1 = wbase[1], t2 = wbase[2], t3 = wbase[3];
        unsigned tot = t0 + t1 + t2 + t3;
        unsigned base = tot ? atomicAdd(&gcnt[(size_t)img * GSTRIDE], tot) : 0u;
        bbase = base;
        wbase[0] = 0; wbase[1] = t0; wbase[2] = t0 + t1; wbase[3] = t0 + t1 + t2;
    }
    __syncthreads();
    unsigned mybase = bbase + wbase[wid];
    unsigned long long lt = (lane == 0) ? 0ull : ((1ull << lane) - 1ull);
    if (c0) {
        unsigned pos = mybase + (unsigned)__popcll(b0 & lt);
        if (pos < (unsigned)CAP)
            keys[(size_t)img * CAP + pos] =
                ((unsigned long long)o0 << 32) | (unsigned)(~(unsigned)p0);
    }
    if (c1) {
        unsigned pos = mybase + (unsigned)__popcll(b0) + (unsigned)__popcll(b1 & lt);
        if (pos < (unsigned)CAP)
            keys[(size_t)img * CAP + pos] =
                ((unsigned long long)o1 << 32) | (unsigned)(~(unsigned)p1);
    }
}

// ---- Multi-block bitonic sort of each image's 8192 keys (descending) ----

// K4a: stages k=2..2048 (all chunk-local). 4 chunks of 2048 per image.
__global__ void __launch_bounds__(1024) k_sloc1(
        unsigned long long* __restrict__ keys, const unsigned* __restrict__ gcnt) {
    __shared__ unsigned long long sk[2048];
    int img = blockIdx.x >> 2;
    int base = (blockIdx.x & 3) * 2048;
    int N = (int)min(gcnt[(size_t)img * GSTRIDE], (unsigned)CAP);
    unsigned long long* kp = keys + (size_t)img * CAP;
    int tid = threadIdx.x;
    for (int i = tid; i < 2048; i += 1024)
        sk[i] = (base + i < N) ? kp[base + i] : 0ull;
    __syncthreads();
    for (int k = 2; k <= 2048; k <<= 1) {
        for (int j = k >> 1; j > 0; j >>= 1) {
            int i = ((tid & ~(j - 1)) << 1) | (tid & (j - 1));
            int p = i | j;
            bool desc = (((base + i) & k) == 0);
            unsigned long long a = sk[i], b = sk[p];
            bool sw = desc ? (a < b) : (a > b);
            if (sw) { sk[i] = b; sk[p] = a; }
            __syncthreads();
        }
    }
    for (int i = tid; i < 2048; i += 1024) kp[base + i] = sk[i];
}

// K4b: stage k=4096 complete (j=2048..1). 2 half-spans of 4096 per image.
__global__ void __launch_bounds__(1024) k_sloc2(unsigned long long* __restrict__ keys) {
    __shared__ unsigned long long sk[4096];
    int img = blockIdx.x >> 1;
    int base = (blockIdx.x & 1) * 4096;
    unsigned long long* kp = keys + (size_t)img * CAP + base;
    int tid = threadIdx.x;
    for (int i = tid; i < 4096; i += 1024) sk[i] = kp[i];
    __syncthreads();
    for (int j = 2048; j > 0; j >>= 1) {
        for (int t = tid; t < 2048; t += 1024) {
            int i = ((t & ~(j - 1)) << 1) | (t & (j - 1));
            int p = i | j;
            bool desc = (((base + i) & 4096) == 0);
            unsigned long long a = sk[i], b = sk[p];
            bool sw = desc ? (a < b) : (a > b);
            if (sw) { sk[i] = b; sk[p] = a; }
        }
        __syncthreads();
    }
    for (int i = tid; i < 4096; i += 1024) kp[i] = sk[i];
}

// K4c: stage k=8192 complete (j=4096..1, all descending). 1 block per image.
__global__ void __launch_bounds__(1024) k_sloc3(unsigned long long* __restrict__ keys) {
    __shared__ unsigned long long sk[CAP];
    unsigned long long* kp = keys + (size_t)blockIdx.x * CAP;
    int tid = threadIdx.x;
    for (int i = tid; i < CAP; i += 1024) sk[i] = kp[i];
    __syncthreads();
    for (int j = 4096; j > 0; j >>= 1) {
        for (int t = tid; t < 4096; t += 1024) {
            int i = ((t & ~(j - 1)) << 1) | (t & (j - 1));
            int p = i | j;
            unsigned long long a = sk[i], b = sk[p];
            if (a < b) { sk[i] = b; sk[p] = a; }     // always descending
        }
        __syncthreads();
    }
    for (int i = tid; i < CAP; i += 1024) kp[i] = sk[i];
}

// K4d: decode sorted top-5000 keys -> SC/X1/Y1/X2/Y2/AREA (fully parallel)
__global__ void __launch_bounds__(256) k_decode(
        const unsigned long long* __restrict__ keys,
        const float* __restrict__ loc, const float* __restrict__ pri,
        float* __restrict__ SC, float* __restrict__ X1, float* __restrict__ Y1,
        float* __restrict__ X2, float* __restrict__ Y2, float* __restrict__ AREA) {
    int gidx = blockIdx.x * 256 + threadIdx.x;
    if (gidx >= BNUM * TOPK) return;
    int img = gidx / TOPK;
    int r = gidx - img * TOPK;
    unsigned long long key = keys[(size_t)img * CAP + r];
    size_t o = (size_t)img * TOPK + r;
    if (key != 0ull) {
        unsigned ordv = (unsigned)(key >> 32);
        float s = ord2f(ordv);
        unsigned p = ~(unsigned)(key & 0xFFFFFFFFull);
        const float* lp = loc + ((size_t)img * PNUM + p) * 4;
        const float* pp = pri + (size_t)p * 4;
        float lx = lp[0], ly = lp[1], lw = lp[2], lh = lp[3];
        float px = pp[0], py = pp[1], pw = pp[2], ph = pp[3];
        float cx = px + (lx * 0.1f) * pw;
        float cy = py + (ly * 0.1f) * ph;
        float w = pw * expf(lw * 0.2f);
        float h = ph * expf(lh * 0.2f);
        float x1 = cx - w * 0.5f;
        float y1 = cy - h * 0.5f;
        float x2 = x1 + w;
        float y2 = y1 + h;
        SC[o] = s; X1[o] = x1; Y1[o] = y1; X2[o] = x2; Y2[o] = y2;
        AREA[o] = (x2 - x1) * (y2 - y1);
    } else {
        SC[o] = -1.0f; X1[o] = 0.f; Y1[o] = 0.f; X2[o] = 0.f; Y2[o] = 0.f;
        AREA[o] = 0.f;
    }
}

// K5a: spatial bucketing by x1 (counting sort into 128 buckets), with
// gathered box copies so the pair scan reads contiguously. 1 block/image.
__global__ void __launch_bounds__(256) k_bucket(
        const float* __restrict__ X1, const float* __restrict__ X2,
        const float* __restrict__ Y1, const float* __restrict__ Y2,
        const float* __restrict__ AREA,
        unsigned* __restrict__ bofs, unsigned* __restrict__ sidx,
        float* __restrict__ sbx1, float* __restrict__ sbx2,
        float* __restrict__ sby1, float* __restrict__ sby2,
        float* __restrict__ sbar) {
    __shared__ unsigned bcnt[NXB], bpre[NXB + 1], bcur[NXB];
    int img = blockIdx.x;
    int tid = threadIdx.x;
    if (tid < NXB) bcnt[tid] = 0;
    __syncthreads();
    size_t ib = (size_t)img * TOPK;
    for (int r = tid; r < TOPK; r += 256)
        atomicAdd(&bcnt[bucketOf(X1[ib + r])], 1u);
    __syncthreads();
    if (tid == 0) {
        unsigned a = 0;
        for (int b = 0; b < NXB; ++b) { bpre[b] = a; a += bcnt[b]; }
        bpre[NXB] = a;
    }
    __syncthreads();
    if (tid < NXB) bcur[tid] = bpre[tid];
    if (tid <= NXB) bofs[img * 130 + tid] = bpre[tid];
    __syncthreads();
    int base = img * BSTRIDE;
    for (int r = tid; r < TOPK; r += 256) {
        float x = X1[ib + r];
        unsigned s = atomicAdd(&bcur[bucketOf(x)], 1u);
        sidx[base + s] = (unsigned)r;
        sbx1[base + s] = x;
        sbx2[base + s] = X2[ib + r];
        sby1[base + s] = Y1[ib + r];
        sby2[base + s] = Y2[ib + r];
        sbar[base + s] = AREA[ib + r];
    }
}

// K5b: WAVE-COOPERATIVE bucketed pair search. One wave per box r: 64 lanes
// stride the candidate range [bofs[b1], bofs[b2+1]) with coalesced loads;
// pair emitted by the box with smaller x1 (tie: smaller original index) ->
// each x-overlapping pair tested exactly once. IoU math bit-identical to
// the reference (fmin/fmax/add commutative). Per-wave ballot-compacted
// emission into an LDS buffer, flushed once per block.
__global__ void __launch_bounds__(256) k_pair2(
        const float* __restrict__ X1, const float* __restrict__ X2,
        const float* __restrict__ Y1, const float* __restrict__ Y2,
        const float* __restrict__ AREA,
        const unsigned* __restrict__ bofs, const unsigned* __restrict__ sidx,
        const float* __restrict__ sbx1, const float* __restrict__ sbx2,
        const float* __restrict__ sby1, const float* __restrict__ sby2,
        const float* __restrict__ sbar,
        unsigned* __restrict__ ecnt, unsigned* __restrict__ edges) {
    __shared__ unsigned ebuf[EBUF];
    __shared__ unsigned ecl, ebase;
    int img = blockIdx.y;
    int wid = threadIdx.x >> 6;
    int lane = threadIdx.x & 63;
    int r = blockIdx.x * 4 + wid;                 // one wave per box
    if (threadIdx.x == 0) ecl = 0;
    __syncthreads();
    unsigned* ec = ecnt + (size_t)img * GSTRIDE;
    unsigned* eg = edges + (size_t)img * CAPE;
    if (r < TOPK) {
        size_t ib = (size_t)img * TOPK;
        float x1 = X1[ib + r], x2 = X2[ib + r];
        float y1 = Y1[ib + r], y2 = Y2[ib + r];
        float ar = AREA[ib + r];
        int b1 = bucketOf(x1), b2 = bucketOf(x2);
        const unsigned* bo = bofs + img * 130;
        unsigned s0 = bo[b1], s1 = bo[b2 + 1];
        int base = img * BSTRIDE;
        for (unsigned sb = s0 + lane; ; sb += 64) {
            bool hit = false;
            unsigned edge = 0;
            if (sb < s1) {
                float bx1 = sbx1[base + sb];
                if (bx1 >= x1) {
                    unsigned r2 = sidx[base + sb];
                    if (!(bx1 == x1 && r2 <= (unsigned)r)) {
                        float bx2 = sbx2[base + sb];
                        float dx = fminf(x2, bx2) - fmaxf(x1, bx1);
                        if (dx > 0.0f) {
                            float by1 = sby1[base + sb];
                            float by2 = sby2[base + sb];
                            float dy = fminf(y2, by2) - fmaxf(y1, by1);
                            if (dy > 0.0f) {
                                float inter = dx * dy;
                                float iou = inter /
                                    (sbar[base + sb] + ar - inter);
                                if (iou > 0.3f) {
                                    unsigned su = ((unsigned)r < r2)
                                                  ? (unsigned)r : r2;
                                    unsigned vi = ((unsigned)r < r2)
                                                  ? r2 : (unsigned)r;
                                    edge = (vi << 13) | su;
                                    hit = true;
                                }
                            }
                        }
                    }
                }
            }
            unsigned long long bal = __ballot(hit);
            if (bal) {
                int n = __popcll(bal);
                unsigned wb = 0;
                if (lane == 0) wb = atomicAdd(&ecl, (unsigned)n);
                wb = __shfl(wb, 0, 64);
                if (hit) {
                    unsigned long long lt =
                        (lane == 0) ? 0ull : ((1ull << lane) - 1ull);
                    unsigned p = wb + (unsigned)__popcll(bal & lt);
                    if (p < (unsigned)EBUF) ebuf[p] = edge;
                    else {
                        unsigned gp = atomicAdd(ec, 1u);
                        if (gp < (unsigned)CAPE) eg[gp] = edge;
                    }
                }
            }
            // uniform across wave: all lanes see same range
            if (sb - lane + 64 >= s1) break;
        }
    }
    __syncthreads();
    unsigned n = min(ecl, (unsigned)EBUF);
    if (threadIdx.x == 0 && n) ebase = atomicAdd(ec, n);
    __syncthreads();
    for (unsigned i = threadIdx.x; i < n; i += 256) {
        unsigned p = ebase + i;
        if (p < (unsigned)CAPE) eg[p] = ebuf[i];
    }
}

// K5c: sparse greedy resolve + compaction. One block (256) per image.
__global__ void __launch_bounds__(256) k_nms2(
        const float* __restrict__ SC, const float* __restrict__ X1,
        const float* __restrict__ Y1, const float* __restrict__ X2,
        const float* __restrict__ Y2,
        const unsigned* __restrict__ ecnt, const unsigned* __restrict__ edges,
        unsigned* __restrict__ grouped, float* __restrict__ out) {
    __shared__ unsigned cnt[80], ofs[80], cur[80];
    __shared__ unsigned long long keepw[80];
    __shared__ unsigned pfx[80];
    __shared__ unsigned inLo[64], inHi[64];
    __shared__ unsigned remS[2];
    int img = blockIdx.x;
    int tid = threadIdx.x;
    int l = tid & 63;
    int wid = tid >> 6;
    size_t ib = (size_t)img * TOPK;
    const float* sc = SC + ib;

    // A: counting sort of edges by victim tile (v>>6 == edge>>19)
    if (tid < 80) cnt[tid] = 0;
    __syncthreads();
    unsigned E = min(ecnt[(size_t)img * GSTRIDE], (unsigned)CAPE);
    const unsigned* eimg = edges + (size_t)img * CAPE;
    unsigned* gimg = grouped + (size_t)img * CAPE;
    for (unsigned e = tid; e < E; e += 256) atomicAdd(&cnt[eimg[e] >> 19], 1u);
    __syncthreads();
    if (tid == 0) {
        unsigned a = 0;
        for (int w = 0; w < NWORDS; ++w) { ofs[w] = a; a += cnt[w]; }
    }
    __syncthreads();
    if (tid < 80) cur[tid] = ofs[tid];
    __syncthreads();
    for (unsigned e = tid; e < E; e += 256) {
        unsigned ed = eimg[e];
        unsigned p = atomicAdd(&cur[ed >> 19], 1u);
        gimg[p] = ed;
    }
    __syncthreads();

    // B: wave-0 serial-over-tiles resolve
    if (wid == 0) {
        for (int t = 0; t < NWORDS; ++t) {
            inLo[l] = 0; inHi[l] = 0;
            if (l < 2) remS[l] = 0;
            int row = t * 64 + l;
            bool valid = (row < TOPK) && (sc[row] > 0.01f);
            unsigned c = cnt[t], o = ofs[t];
            for (unsigned k = l; k < c; k += 64) {
                unsigned ed = gimg[o + k];
                unsigned v = ed >> 13, s = ed & 8191u;
                unsigned vb = v & 63u, sb = s & 63u;
                int st = (int)(s >> 6);
                if (st == t) {
                    if (sb < 32) atomicOr(&inLo[vb], 1u << sb);
                    else         atomicOr(&inHi[vb], 1u << (sb - 32));
                } else {
                    unsigned long long kw = keepw[st];   // finalized (st < t)
                    if ((kw >> sb) & 1ull) {
                        if (vb < 32) atomicOr(&remS[0], 1u << vb);
                        else         atomicOr(&remS[1], 1u << (vb - 32));
                    }
                }
            }
            __builtin_amdgcn_s_waitcnt(0);   // drain LDS atomics before reads
            unsigned long long inW =
                ((unsigned long long)inHi[l] << 32) | inLo[l];
            unsigned long long remW =
                ((unsigned long long)remS[1] << 32) | remS[0];
            bool alive = valid && !((remW >> l) & 1ull);
            while (true) {                   // exact ascending greedy
                unsigned long long aliveW = __ballot(alive);
                unsigned long long pend =
                    __ballot(alive && ((inW & aliveW) != 0ull));
                if (!pend) break;
                int v = __builtin_ctzll(pend);
                if (l == v) alive = false;
            }
            unsigned long long kwv = __ballot(alive);
            if (l == 0) keepw[t] = kwv;
        }
    }
    __syncthreads();

    // C: prefix + compacted output write
    if (tid == 0) {
        unsigned acc = 0;
        for (int w = 0; w < NWORDS; ++w) { pfx[w] = acc; acc += (unsigned)__popcll(keepw[w]); }
    }
    __syncthreads();
    const float* x1 = X1 + ib; const float* y1 = Y1 + ib;
    const float* x2 = X2 + ib; const float* y2 = Y2 + ib;
    float* op = out + (((size_t)img * 2) + 1) * TOPK * 5;
    for (int w = wid; w < NWORDS; w += 4) {
        unsigned long long kw = keepw[w];
        if (!kw) continue;
        int row = w * 64 + l;
        if ((kw >> l) & 1ull) {
            int rank = (int)pfx[w] + (int)__popcll(kw & ((1ull << l) - 1ull));
            float* r = op + (size_t)rank * 5;
            r[0] = sc[row]; r[1] = x1[row]; r[2] = y1[row];
            r[3] = x2[row]; r[4] = y2[row];
        }
    }
}

extern "C" void kernel_launch(void* const* d_in, const int* in_sizes, int n_in,
                              void* d_out, int out_size, void* d_ws, size_t ws_size,
                              hipStream_t stream) {
    (void)in_sizes; (void)n_in; (void)ws_size;
    const float* loc  = (const float*)d_in[0];   // (16, 136500, 4)
    const float* conf = (const float*)d_in[1];   // (16*136500, 2)
    const float* pri  = (const float*)d_in[2];   // (136500, 4)
    float* out = (float*)d_out;                  // (16, 2, 5000, 5)
    char* ws = (char*)d_ws;

    float* SC   = (float*)(ws + OFF_SC);
    float* X1   = (float*)(ws + OFF_X1);
    float* Y1   = (float*)(ws + OFF_Y1);
    float* X2   = (float*)(ws + OFF_X2);
    float* Y2   = (float*)(ws + OFF_Y2);
    float* AREA = (float*)(ws + OFF_AREA);
    unsigned* hist = (unsigned*)(ws + OFF_HIST);
    unsigned* cut  = (unsigned*)(ws + OFF_CUT);
    unsigned* gcnt = (unsigned*)(ws + OFF_GCNT);
    unsigned long long* keys = (unsigned long long*)(ws + OFF_KEYS);
    unsigned* ecnt = (unsigned*)(ws + OFF_ECNT);
    unsigned* edges = (unsigned*)(ws + OFF_EDGE);
    unsigned* grouped = (unsigned*)(ws + OFF_GRP);
    unsigned* bofs = (unsigned*)(ws + OFF_BOFS);
    unsigned* sidx = (unsigned*)(ws + OFF_SIDX);
    float* sbx1 = (float*)(ws + OFF_SBX1);
    float* sbx2 = (float*)(ws + OFF_SBX2);
    float* sby1 = (float*)(ws + OFF_SBY1);
    float* sby2 = (float*)(ws + OFF_SBY2);
    float* sbar = (float*)(ws + OFF_SBAR);

    hipMemsetAsync(d_out, 0, (size_t)out_size * sizeof(float), stream);
    // zero hist+cut+gcnt (+keys harmlessly) + ecnt in one contiguous range
    hipMemsetAsync(ws + OFF_HIST, 0, (OFF_ECNT + 2048) - OFF_HIST, stream);

    dim3 gh1(16, BNUM);                          // 16 grid-stride blocks/image
    k_hist<<<gh1, 256, 0, stream>>>(conf, hist);
    k_cutoff<<<BNUM, 256, 0, stream>>>(hist, cut);
    dim3 gh2((HPNUM + 255) / 256, BNUM);
    k_gather<<<gh2, 256, 0, stream>>>(conf, cut, gcnt, keys);
    // multi-block bitonic sort + parallel decode
    k_sloc1<<<BNUM * 4, 1024, 0, stream>>>(keys, gcnt);
    k_sloc2<<<BNUM * 2, 1024, 0, stream>>>(keys);
    k_sloc3<<<BNUM, 1024, 0, stream>>>(keys);
    k_decode<<<(BNUM * TOPK + 255) / 256, 256, 0, stream>>>(
        keys, loc, pri, SC, X1, Y1, X2, Y2, AREA);

    // sparse NMS: spatial bucketing + wave-cooperative pair search + resolve
    k_bucket<<<BNUM, 256, 0, stream>>>(X1, X2, Y1, Y2, AREA,
                                       bofs, sidx, sbx1, sbx2, sby1, sby2, sbar);
    dim3 pg((TOPK + 3) / 4, BNUM);               // one wave per box
    k_pair2<<<pg, 256, 0, stream>>>(X1, X2, Y1, Y2, AREA,
                                    bofs, sidx, sbx1, sbx2, sby1, sby2, sbar,
                                    ecnt, edges);
    k_nms2<<<BNUM, 256, 0, stream>>>(SC, X1, Y1, X2, Y2, ecnt, edges, grouped, out);
}